// Round 6
// baseline (169.425 us; speedup 1.0000x reference)
//
#include <hip/hip_runtime.h>

#define NCLS 91
#define NP (NCLS * NCLS)          // 8281 pair bins
#define NPPAD 8320                // padded for uint4 zeroing
#define NHIST (3 * NCLS)          // ws: cnt_in | cnt_tg | inter
#define BS 256
#define NWAVES 4                  // BS/64
#define NT 16                     // tiles per wave
#define CHUNK 64                  // float4 per stage instruction (one per lane)

typedef const __attribute__((address_space(1))) void* gas_t;
typedef __attribute__((address_space(3))) void* las_t;

__global__ __launch_bounds__(BS) void miou_hist(const float* __restrict__ inp,
                                                const int* __restrict__ tgt,
                                                unsigned int* __restrict__ ws) {
    __shared__ unsigned int ph[NPPAD];                    // 33,280 B pair table
    __shared__ float4 sbuf[NWAVES][2][2][CHUNK];          // 16,384 B stage buffers

    uint4* z = (uint4*)ph;
    for (int i = threadIdx.x; i < NPPAD / 4; i += BS) z[i] = make_uint4(0u, 0u, 0u, 0u);
    __syncthreads();

    const int w = threadIdx.x >> 6;
    const int l = threadIdx.x & 63;
    const long base = ((long)blockIdx.x * NWAVES + w) * NT;   // this wave's chunk base
    const float4* in4 = (const float4*)inp;
    const int4*  tg4 = (const int4*)tgt;

    auto stage = [&](int slot, int it) {
        const float4* g0 = in4 + (base + it) * CHUNK + l;     // per-lane global src
        const int4*  g1 = tg4 + (base + it) * CHUNK + l;
        // LDS dest is wave-uniform base; HW adds lane*16. Fire-and-forget, no VGPR.
        __builtin_amdgcn_global_load_lds((gas_t)g0, (las_t)&sbuf[w][slot][0][0], 16, 0, 0);
        __builtin_amdgcn_global_load_lds((gas_t)g1, (las_t)&sbuf[w][slot][1][0], 16, 0, 0);
    };

    auto process = [&](int slot) {
        float4 f = sbuf[w][slot][0][l];                       // ds_read_b128
        int4  t = *(const int4*)&sbuf[w][slot][1][l];         // ds_read_b128
        int a0 = (int)f.x, a1 = (int)f.y, a2 = (int)f.z, a3 = (int)f.w;
        atomicAdd(&ph[a0 * NCLS + t.x], 1u);
        atomicAdd(&ph[a1 * NCLS + t.y], 1u);
        atomicAdd(&ph[a2 * NCLS + t.z], 1u);
        atomicAdd(&ph[a3 * NCLS + t.w], 1u);
    };

    stage(0, 0);
    stage(1, 1);
    #pragma unroll
    for (int it = 0; it < NT; ++it) {
        // Invariant at entry: outstanding = stages(it) [oldest 2] + stages(it+1).
        if (it < NT - 1) {
            asm volatile("s_waitcnt vmcnt(2)" ::: "memory");  // tile `it` landed; keep it+1 in flight
        } else {
            asm volatile("s_waitcnt vmcnt(0)" ::: "memory");  // last tile: full drain
        }
        __builtin_amdgcn_sched_barrier(0);
        process(it & 1);
        if (it + 2 < NT) stage(it & 1, it + 2);
    }
    __syncthreads();

    // Fold. Threads 0..90: row sums (cnt_in) + diagonal (inter). 128..218: col sums (cnt_tg).
    int t = threadIdx.x;
    if (t < NCLS) {
        const unsigned int* p = ph + t * NCLS;
        unsigned int s0 = 0, s1 = 0, s2 = 0, s3 = 0;
        int k = 0;
        for (; k + 3 < NCLS; k += 4) { s0 += p[k]; s1 += p[k+1]; s2 += p[k+2]; s3 += p[k+3]; }
        for (; k < NCLS; ++k) s0 += p[k];
        unsigned int s = s0 + s1 + s2 + s3;
        if (s) atomicAdd(&ws[t], s);
        unsigned int d = p[t];
        if (d) atomicAdd(&ws[2 * NCLS + t], d);
    } else if (t >= 128 && t < 128 + NCLS) {
        int c = t - 128;
        unsigned int s0 = 0, s1 = 0, s2 = 0, s3 = 0;
        int a = 0;
        for (; a + 3 < NCLS; a += 4) {
            s0 += ph[a * NCLS + c];
            s1 += ph[(a + 1) * NCLS + c];
            s2 += ph[(a + 2) * NCLS + c];
            s3 += ph[(a + 3) * NCLS + c];
        }
        for (; a < NCLS; ++a) s0 += ph[a * NCLS + c];
        unsigned int s = s0 + s1 + s2 + s3;
        if (s) atomicAdd(&ws[NCLS + c], s);
    }
}

// Generic tail (not launched for the 64x512x512 shape; kept for divisibility safety).
__global__ void miou_tail(const float* __restrict__ inp, const int* __restrict__ tgt,
                          unsigned int* __restrict__ ws, int e0, int n) {
    int i = e0 + blockIdx.x * 256 + threadIdx.x;
    if (i < n) {
        int a = (int)inp[i];
        int t = tgt[i];
        atomicAdd(&ws[a], 1u);
        atomicAdd(&ws[NCLS + t], 1u);
        if (a == t) atomicAdd(&ws[2 * NCLS + a], 1u);
    }
}

__global__ void miou_finalize(const unsigned int* __restrict__ ws,
                              const int* __restrict__ smooth_p,
                              float* __restrict__ out) {
    int lane = threadIdx.x;  // 64 threads
    float s = (float)(*smooth_p);
    float acc = 0.f;
    for (int c = 1 + lane; c < NCLS; c += 64) {
        float ci = (float)ws[c];
        float ct = (float)ws[NCLS + c];
        float it = (float)ws[2 * NCLS + c];
        float un = ci + ct - it;
        acc += (it + s) / (un + s);
    }
    #pragma unroll
    for (int off = 32; off; off >>= 1) acc += __shfl_down(acc, off);
    if (lane == 0) out[0] = acc / (float)(NCLS - 1);
}

extern "C" void kernel_launch(void* const* d_in, const int* in_sizes, int n_in,
                              void* d_out, int out_size, void* d_ws, size_t ws_size,
                              hipStream_t stream) {
    const float* inp = (const float*)d_in[0];
    const int* tgt = (const int*)d_in[1];
    const int* smooth_p = (const int*)d_in[2];
    float* out = (float*)d_out;
    unsigned int* ws = (unsigned int*)d_ws;

    int n = in_sizes[0];                  // 16,777,216
    int n4 = n >> 2;                      // 4,194,304
    int nblk = n4 / (NWAVES * NT * CHUNK);  // 1024 for this shape
    int e0 = nblk * NWAVES * NT * CHUNK * 4;

    hipMemsetAsync(ws, 0, NHIST * sizeof(unsigned int), stream);
    if (nblk > 0)
        miou_hist<<<nblk, BS, 0, stream>>>(inp, tgt, ws);
    if (e0 < n)
        miou_tail<<<(n - e0 + 255) / 256, 256, 0, stream>>>(inp, tgt, ws, e0, n);
    miou_finalize<<<1, 64, 0, stream>>>(ws, smooth_p, out);
}

// Round 7
// 165.330 us; speedup vs baseline: 1.0248x; 1.0248x over previous
//
#include <hip/hip_runtime.h>

#define NCLS 91
#define NW 46                      // packed words per row: 2 target-classes per u32
#define NPW (NCLS * NW)            // 4186 packed words
#define NPPAD 4192                 // padded to /4 for uint4 zeroing
#define NHIST (3 * NCLS)           // ws: cnt_in | cnt_tg | inter
#define BS 256
#define NWAVES 4
#define NT 32                      // tiles per wave (compile-time unrolled)
#define D 6                        // ring depth (tiles); 5 in flight steady-state
#define CHUNK 64                   // float4 per DMA (one per lane)

typedef const __attribute__((address_space(1))) void* gas_t;
typedef __attribute__((address_space(3))) void* las_t;

__global__ __launch_bounds__(BS) void miou_hist(const float* __restrict__ inp,
                                                const int* __restrict__ tgt,
                                                unsigned int* __restrict__ ws) {
    __shared__ unsigned int ph[NPPAD];                 // 16,768 B packed pair table
    __shared__ float4 sbuf[NWAVES][D][2][CHUNK];       // 49,152 B DMA ring

    uint4* z = (uint4*)ph;
    for (int i = threadIdx.x; i < NPPAD / 4; i += BS) z[i] = make_uint4(0u, 0u, 0u, 0u);
    __syncthreads();

    const int w = threadIdx.x >> 6;
    const int l = threadIdx.x & 63;
    const long base = ((long)blockIdx.x * NWAVES + w) * NT;
    const float4* in4 = (const float4*)inp;
    const int4*  tg4 = (const int4*)tgt;

    auto stage = [&](int slot, int tile) {   // tile in [0,NT)
        const float4* g0 = in4 + (base + tile) * CHUNK + l;
        const int4*  g1 = tg4 + (base + tile) * CHUNK + l;
        __builtin_amdgcn_global_load_lds((gas_t)g0, (las_t)&sbuf[w][slot][0][0], 16, 0, 0);
        __builtin_amdgcn_global_load_lds((gas_t)g1, (las_t)&sbuf[w][slot][1][0], 16, 0, 0);
    };

    auto pin = [&](int a, int tv) {
        // packed bin: word = a*46 + tv/2, halfword = tv&1 (no carry: max 16384/bin)
        atomicAdd(&ph[a * NW + (tv >> 1)], 1u << ((tv & 1) << 4));
    };

    // Prologue: stage tiles 0..D-2 (10 DMAs in flight).
    #pragma unroll
    for (int p = 0; p < D - 1; ++p) stage(p, p);

    #pragma unroll
    for (int it = 0; it < NT; ++it) {
        asm volatile("s_waitcnt vmcnt(%0)" :: "i"(2 * (D - 2)) : "memory");
        __builtin_amdgcn_sched_barrier(0);
        // Stage-ahead into the slot consumed last iteration. Last D-1 stages
        // wrap to re-load early tiles as dummies (never read; drained at barrier).
        stage((it + D - 1) % D, (it + D - 1) % NT);
        float4 f = sbuf[w][it % D][0][l];
        int4  t = *(const int4*)&sbuf[w][it % D][1][l];
        pin((int)f.x, t.x);
        pin((int)f.y, t.y);
        pin((int)f.z, t.z);
        pin((int)f.w, t.w);
    }
    __syncthreads();   // drains dummy DMAs + all ds ops before fold

    // Fold packed table. Threads 0..90: rows (cnt_in) + diag (inter); 128..218: cols (cnt_tg).
    int t = threadIdx.x;
    if (t < NCLS) {
        const unsigned int* p = ph + t * NW;
        unsigned int s = 0;
        #pragma unroll 2
        for (int k = 0; k < NW; ++k) { unsigned int v = p[k]; s += (v & 0xFFFFu) + (v >> 16); }
        if (s) atomicAdd(&ws[t], s);
        unsigned int dv = p[t >> 1];
        unsigned int d = (t & 1) ? (dv >> 16) : (dv & 0xFFFFu);
        if (d) atomicAdd(&ws[2 * NCLS + t], d);
    } else if (t >= 128 && t < 128 + NCLS) {
        int c = t - 128;
        int sh = (c & 1) << 4;
        unsigned int s = 0;
        #pragma unroll 2
        for (int a = 0; a < NCLS; ++a) s += (ph[a * NW + (c >> 1)] >> sh) & 0xFFFFu;
        if (s) atomicAdd(&ws[NCLS + c], s);
    }
}

// Generic tail (not launched for the 64x512x512 shape).
__global__ void miou_tail(const float* __restrict__ inp, const int* __restrict__ tgt,
                          unsigned int* __restrict__ ws, int e0, int n) {
    int i = e0 + blockIdx.x * 256 + threadIdx.x;
    if (i < n) {
        int a = (int)inp[i];
        int t = tgt[i];
        atomicAdd(&ws[a], 1u);
        atomicAdd(&ws[NCLS + t], 1u);
        if (a == t) atomicAdd(&ws[2 * NCLS + a], 1u);
    }
}

__global__ void miou_finalize(const unsigned int* __restrict__ ws,
                              const int* __restrict__ smooth_p,
                              float* __restrict__ out) {
    int lane = threadIdx.x;  // 64 threads
    float s = (float)(*smooth_p);
    float acc = 0.f;
    for (int c = 1 + lane; c < NCLS; c += 64) {
        float ci = (float)ws[c];
        float ct = (float)ws[NCLS + c];
        float it = (float)ws[2 * NCLS + c];
        float un = ci + ct - it;
        acc += (it + s) / (un + s);
    }
    #pragma unroll
    for (int off = 32; off; off >>= 1) acc += __shfl_down(acc, off);
    if (lane == 0) out[0] = acc / (float)(NCLS - 1);
}

extern "C" void kernel_launch(void* const* d_in, const int* in_sizes, int n_in,
                              void* d_out, int out_size, void* d_ws, size_t ws_size,
                              hipStream_t stream) {
    const float* inp = (const float*)d_in[0];
    const int* tgt = (const int*)d_in[1];
    const int* smooth_p = (const int*)d_in[2];
    float* out = (float*)d_out;
    unsigned int* ws = (unsigned int*)d_ws;

    int n = in_sizes[0];                       // 16,777,216
    int eper = BS * 4 * NT;                    // 32768 elements per block
    int nblk = n / eper;                       // 512
    int e0 = nblk * eper;

    hipMemsetAsync(ws, 0, NHIST * sizeof(unsigned int), stream);
    if (nblk > 0)
        miou_hist<<<nblk, BS, 0, stream>>>(inp, tgt, ws);
    if (e0 < n)
        miou_tail<<<(n - e0 + 255) / 256, 256, 0, stream>>>(inp, tgt, ws, e0, n);
    miou_finalize<<<1, 64, 0, stream>>>(ws, smooth_p, out);
}